// Round 6
// baseline (1393.565 us; speedup 1.0000x reference)
//
#include <hip/hip_runtime.h>

typedef float v2f __attribute__((ext_vector_type(2)));
typedef float v4f __attribute__((ext_vector_type(4)));

#define LOG2E 1.4426950408889634f
#define LN2   0.6931471805599453f

__device__ __forceinline__ float fexp2(float x) {
  float r; asm("v_exp_f32 %0, %1" : "=v"(r) : "v"(x)); return r;
}
__device__ __forceinline__ float fexp2n(float x) {   // exp2(-x), modifier is free
  float r; asm("v_exp_f32 %0, -%1" : "=v"(r) : "v"(x)); return r;
}
__device__ __forceinline__ float frcp(float x) {
  float r; asm("v_rcp_f32 %0, %1" : "=v"(r) : "v"(x)); return r;
}
__device__ __forceinline__ float flog2(float x) {
  float r; asm("v_log_f32 %0, %1" : "=v"(r) : "v"(x)); return r;
}
// packed fp32 FMA, accumulate in place
__device__ __forceinline__ void pkfma(v2f& c, v2f a, v2f b) {
  asm("v_pk_fma_f32 %0, %1, %2, %0" : "+v"(c) : "v"(a), "v"(b));
}
// quad_perm lane swaps (VALU pipe)
__device__ __forceinline__ float dpp_xor1(float v) {
  return __builtin_bit_cast(float,
      __builtin_amdgcn_update_dpp(0, __builtin_bit_cast(int, v), 0xB1, 0xF, 0xF, true));
}
__device__ __forceinline__ float dpp_xor2(float v) {
  return __builtin_bit_cast(float,
      __builtin_amdgcn_update_dpp(0, __builtin_bit_cast(int, v), 0x4E, 0xF, 0xF, true));
}
// workgroup barrier WITHOUT vmcnt(0) drain: LDS ordering only
__device__ __forceinline__ void barrier_lgkm() {
  asm volatile("s_waitcnt lgkmcnt(0)\n\ts_barrier" ::: "memory");
}

// ---------------- fused prep: embed | repack0 | repack1 | wab | misc | bscale ------
// grid 3241 x 128 threads; block ranges select the job.
__global__ __launch_bounds__(128) void k_prep(
    const float* __restrict__ wv, const int* __restrict__ pidx,
    const float* __restrict__ pemb, float* __restrict__ X,
    const float* __restrict__ Wih0, float* __restrict__ Wih0p,
    const float* __restrict__ Wih1, float* __restrict__ Wih1p,
    const float* __restrict__ fc1W, float* __restrict__ Wab,
    const float* __restrict__ fc1b, const float* __restrict__ fc2W,
    float* __restrict__ biasAB, float* __restrict__ sumw,
    const float* __restrict__ b0, float* __restrict__ bs0,
    const float* __restrict__ b1, float* __restrict__ bs1) {
  const int b = blockIdx.x, tid = threadIdx.x;
  if (b < 1024) {                       // embed
    int t = b, pi = pidx[t];
    for (int c = tid; c < 336; c += 128) {
      float v;
      if (c < 300)      v = wv[t * 300 + c];
      else if (c < 325) v = pemb[pi * 25 + (c - 300)];
      else              v = 0.f;
      X[t * 336 + c] = v;
    }
  } else if (b < 2024) {                // repack Wih0 (scale quarter-exp2)
    int r = b - 1024;
    int gate = (r % 500) / 125;
    float sc = (gate == 2) ? 0.5f * LOG2E : 0.25f * LOG2E;
    for (int c = tid; c < 336; c += 128)
      Wih0p[r * 336 + c] = (c < 325) ? Wih0[r * 325 + c] * sc : 0.f;
  } else if (b < 3024) {                // repack Wih1
    int r = b - 2024;
    int gate = (r % 500) / 125;
    float sc = (gate == 2) ? 0.5f * LOG2E : 0.25f * LOG2E;
    for (int c = tid; c < 256; c += 128)
      Wih1p[r * 256 + c] = (c < 250) ? Wih1[r * 250 + c] * sc : 0.f;
  } else if (b < 3224) {                // wab split
    int r = b - 3024;
    int sr = (r < 100) ? r : r - 100;
    int so = (r < 100) ? 0 : 250;
    for (int c = tid; c < 256; c += 128)
      Wab[r * 256 + c] = (c < 250) ? fc1W[sr * 500 + so + c] : 0.f;
  } else if (b == 3224) {               // biasAB + sum(fc2W)
    __shared__ float red[128];
    for (int c = tid; c < 256; c += 128)
      biasAB[c] = (c < 100) ? fc1b[c] : 0.f;
    float s = (tid < 100) ? fc2W[tid] : 0.f;
    red[tid] = s; __syncthreads();
    for (int off = 64; off; off >>= 1) {
      if (tid < off) red[tid] += red[tid + off];
      __syncthreads();
    }
    if (tid == 0) sumw[0] = red[0];
  } else if (b < 3233) {                // bscale layer 0
    int i = (b - 3225) * 128 + tid;
    if (i < 1000) {
      int gate = (i % 500) / 125;
      bs0[i] = b0[i] * ((gate == 2) ? 0.5f * LOG2E : 0.25f * LOG2E);
    }
  } else {                              // bscale layer 1
    int i = (b - 3233) * 128 + tid;
    if (i < 1000) {
      int gate = (i % 500) / 125;
      bs1[i] = b1[i] * ((gate == 2) ? 0.5f * LOG2E : 0.25f * LOG2E);
    }
  }
}

// ---------------- tiled fp32 GEMM:  C = A @ B^T + bias -----------------------------
// transOut=0: C[m][n]. transOut=2: gate-interleaved scatter for k_rec:
//   C[(n%125)*4096 + m*4 + (n/125)]
#define BM 64
#define BN 64
#define BKK 16
__global__ __launch_bounds__(256) void k_gemm(
    const float* __restrict__ A, const float* __restrict__ Bw,
    const float* __restrict__ bias, float* __restrict__ C,
    int M, int N, int K, int ldC, long sBz, long sCz, long sbz, int transOut) {
  const int z = blockIdx.z;
  const float* Bp = Bw + (size_t)z * sBz;
  const float* bp = bias + (size_t)z * sbz;
  float* Cp = C + (size_t)z * sCz;
  const int bm = blockIdx.y * BM, bn = blockIdx.x * BN;
  __shared__ __align__(16) float As[BKK][BM + 4];
  __shared__ __align__(16) float Bs[BKK][BN + 4];
  const int tid = threadIdx.x;
  const int tx = tid & 15, ty = tid >> 4;
  const int lr = tid >> 2;            // 0..63
  const int lk = (tid & 3) * 4;       // 0,4,8,12
  float acc[4][4];
#pragma unroll
  for (int a = 0; a < 4; ++a)
#pragma unroll
    for (int b = 0; b < 4; ++b) acc[a][b] = 0.f;

  int brow = bn + lr; if (brow >= N) brow = N - 1;
  for (int k0 = 0; k0 < K; k0 += BKK) {
    float4 a4 = *(const float4*)(A + (size_t)(bm + lr) * K + k0 + lk);
    float4 b4 = *(const float4*)(Bp + (size_t)brow * K + k0 + lk);
    __syncthreads();
    As[lk + 0][lr] = a4.x; As[lk + 1][lr] = a4.y; As[lk + 2][lr] = a4.z; As[lk + 3][lr] = a4.w;
    Bs[lk + 0][lr] = b4.x; Bs[lk + 1][lr] = b4.y; Bs[lk + 2][lr] = b4.z; Bs[lk + 3][lr] = b4.w;
    __syncthreads();
#pragma unroll
    for (int kk = 0; kk < BKK; ++kk) {
      float4 av = *(const float4*)&As[kk][ty * 4];
      float4 bv = *(const float4*)&Bs[kk][tx * 4];
      float aa[4] = {av.x, av.y, av.z, av.w};
      float bb[4] = {bv.x, bv.y, bv.z, bv.w};
#pragma unroll
      for (int a = 0; a < 4; ++a)
#pragma unroll
        for (int b = 0; b < 4; ++b)
          acc[a][b] = __builtin_fmaf(aa[a], bb[b], acc[a][b]);
    }
  }
  if (transOut == 0) {
#pragma unroll
    for (int a = 0; a < 4; ++a) {
      int i = bm + ty * 4 + a;
#pragma unroll
      for (int b = 0; b < 4; ++b) {
        int j = bn + tx * 4 + b;
        if (j < N) Cp[(size_t)i * ldC + j] = acc[a][b] + bp[j];
      }
    }
  } else {
#pragma unroll
    for (int a = 0; a < 4; ++a) {
      int i = bm + ty * 4 + a;      // time
#pragma unroll
      for (int b = 0; b < 4; ++b) {
        int j = bn + tx * 4 + b;    // gate-row
        if (j < N) {
          int g = j / 125, u2 = j - g * 125;
          Cp[(size_t)u2 * 4096 + i * 4 + g] = acc[a][b] + bp[j];
        }
      }
    }
  }
}

// ---------------- LSTM recurrence v6 ----------------------------------------------
// Same inner structure as v5 (zero-conflict LDS, quad reduce-all, 1 lgkm barrier/step)
// PLUS: 128-block redundant dispatch (clock-governor probe/exploit) — all blocks do
// identical serial work; only blocks 0 (fwd) and 1 (bwd) write hout.
// c kept pre-scaled by 2*LOG2E to shorten the tanh chain.
#define REC_BODY(FWD)                                                              \
  {                                                                                \
    float cst = 0.f;                                                               \
    float4 cur[4], nxt[4];                                                         \
    _Pragma("unroll")                                                              \
    for (int e = 0; e < 4; ++e) cur[e] = Pr4[(FWD ? 0 : 1020) + e];                \
    __syncthreads();                                                               \
    for (int cb = 0; cb < 256; ++cb) {                                             \
      int nc = (cb + 1 < 256) ? cb + 1 : cb;                                       \
      int nb = FWD ? 4 * nc : 1020 - 4 * nc;                                       \
      _Pragma("unroll")                                                            \
      for (int e = 0; e < 4; ++e) nxt[e] = Pr4[nb + e];                            \
      _Pragma("unroll")                                                            \
      for (int e = 0; e < 4; ++e) {                                                \
        const int buf = e & 1;                                                     \
        float4 pre = cur[FWD ? e : 3 - e];                                         \
        const v4f* hp = (const v4f*)&hb[buf][36 * sub];                            \
        v2f a0 = {0.f, 0.f}, a1 = {0.f, 0.f}, a2 = {0.f, 0.f}, a3 = {0.f, 0.f};    \
        _Pragma("unroll")                                                          \
        for (int q = 0; q < 4; ++q) {                                              \
          v4f h1v = hp[2 * q], h2v = hp[2 * q + 1];                                \
          v2f ha = __builtin_shufflevector(h1v, h1v, 0, 1);                        \
          v2f hc = __builtin_shufflevector(h1v, h1v, 2, 3);                        \
          v2f he = __builtin_shufflevector(h2v, h2v, 0, 1);                        \
          v2f hg = __builtin_shufflevector(h2v, h2v, 2, 3);                        \
          pkfma(a0, w0[4 * q], ha); pkfma(a0, w0[4 * q + 1], hc);                  \
          pkfma(a0, w0[4 * q + 2], he); pkfma(a0, w0[4 * q + 3], hg);              \
          pkfma(a1, w1[4 * q], ha); pkfma(a1, w1[4 * q + 1], hc);                  \
          pkfma(a1, w1[4 * q + 2], he); pkfma(a1, w1[4 * q + 3], hg);              \
          pkfma(a2, w2[4 * q], ha); pkfma(a2, w2[4 * q + 1], hc);                  \
          pkfma(a2, w2[4 * q + 2], he); pkfma(a2, w2[4 * q + 3], hg);              \
          pkfma(a3, w3[4 * q], ha); pkfma(a3, w3[4 * q + 1], hc);                  \
          pkfma(a3, w3[4 * q + 2], he); pkfma(a3, w3[4 * q + 3], hg);              \
        }                                                                          \
        float p0 = a0.x + a0.y + pre.x;                                            \
        float p1 = a1.x + a1.y + pre.y;                                            \
        float p2 = a2.x + a2.y + pre.z;                                            \
        float p3 = a3.x + a3.y + pre.w;                                            \
        p0 += dpp_xor1(p0); p0 += dpp_xor2(p0);                                    \
        p1 += dpp_xor1(p1); p1 += dpp_xor2(p1);                                    \
        p2 += dpp_xor1(p2); p2 += dpp_xor2(p2);                                    \
        p3 += dpp_xor1(p3); p3 += dpp_xor2(p3);                                    \
        float gi = frcp(1.f + fexp2n(p0));                                         \
        float gf = frcp(1.f + fexp2n(p1));                                         \
        /* gg pre-scaled by 2*LOG2E: gg2 = 2LOG2E*(2*sig-1) */                     \
        float gg2 = __builtin_fmaf(4.f * LOG2E, frcp(1.f + fexp2n(p2)),            \
                                   -2.f * LOG2E);                                  \
        float go = frcp(1.f + fexp2n(p3));                                         \
        cst = __builtin_fmaf(gf, cst, gi * gg2);   /* c scaled by 2*LOG2E */       \
        float th = __builtin_fmaf(2.f, frcp(1.f + fexp2n(cst)), -1.f);             \
        float h = go * th;                                                         \
        if (wr) {                                                                  \
          hb[buf ^ 1][u + 4 * (u >> 5)] = h;                                       \
          int step = 4 * cb + e;                                                   \
          int time = FWD ? step : 1023 - step;                                     \
          hout[(size_t)time * 256 + d * 125 + u] = h;                              \
        } else if (sub == 0) {                                                     \
          hb[buf ^ 1][u + 4 * (u >> 5)] = h;                                       \
        }                                                                          \
        barrier_lgkm();                                                            \
      }                                                                            \
      cur[0] = nxt[0]; cur[1] = nxt[1]; cur[2] = nxt[2]; cur[3] = nxt[3];          \
    }                                                                              \
  }

__global__ __launch_bounds__(512, 2) void k_rec(const float* __restrict__ Pq,
                                                const float* __restrict__ Whh,
                                                float* __restrict__ hout) {
  const int d = blockIdx.x & 1;
  const int t = threadIdx.x;
  int u = t >> 2; if (u > 124) u = 124;
  const int sub = t & 3;
  const bool wr = (sub == 0) && ((t >> 2) < 125) && (blockIdx.x < 2);

  // weights: 4 gate rows x 32 cols (sub chunk) -> 128 VGPRs, exp2-domain scaled
  const float* Wd = Whh + (size_t)d * 500 * 125;
  v2f w0[16], w1[16], w2[16], w3[16];
#pragma unroll
  for (int j = 0; j < 16; ++j) {
    int col = sub * 32 + 2 * j;
    const float* r0 = Wd + (size_t)(0 * 125 + u) * 125;
    const float* r1 = Wd + (size_t)(1 * 125 + u) * 125;
    const float* r2 = Wd + (size_t)(2 * 125 + u) * 125;
    const float* r3 = Wd + (size_t)(3 * 125 + u) * 125;
    bool c0 = col < 125, c1 = col + 1 < 125;
    v2f a, b, c, dd;
    a.x  = c0 ? r0[col] * LOG2E : 0.f;          a.y  = c1 ? r0[col + 1] * LOG2E : 0.f;
    b.x  = c0 ? r1[col] * LOG2E : 0.f;          b.y  = c1 ? r1[col + 1] * LOG2E : 0.f;
    c.x  = c0 ? r2[col] * 2.f * LOG2E : 0.f;    c.y  = c1 ? r2[col + 1] * 2.f * LOG2E : 0.f;
    dd.x = c0 ? r3[col] * LOG2E : 0.f;          dd.y = c1 ? r3[col + 1] * LOG2E : 0.f;
    w0[j] = a; w1[j] = b; w2[j] = c; w3[j] = dd;
  }

  __shared__ __align__(16) float hb[2][160];   // padded: addr(c)=c+4*(c>>5)
  for (int i = t; i < 320; i += 512) ((float*)hb)[i] = 0.f;

  const float4* Pr4 = (const float4*)(Pq + (size_t)d * 500 * 1024) + (size_t)u * 1024;

  if (d == 0) REC_BODY(1)
  else        REC_BODY(0)
}

// ---------------- pairwise scorer ---------------------------------------------------
__global__ __launch_bounds__(256) void k_pair(const float* __restrict__ AB,
    const float* __restrict__ fc2W, const float* __restrict__ fc2b,
    const float* __restrict__ sumw, float* __restrict__ outS,
    float* __restrict__ scoresT) {
  __shared__ float As[32][100];
  __shared__ float Bs[32][101];
  __shared__ float w2s[100];
  const int tid = threadIdx.x;
  const int i0 = blockIdx.y * 32, j0 = blockIdx.x * 32;
  for (int idx = tid; idx < 3200; idx += 256) {
    int r = idx / 100, k = idx - r * 100;
    As[r][k] = AB[(size_t)(i0 + r) * 200 + k];
    Bs[r][k] = AB[(size_t)(j0 + r) * 200 + 100 + k];
  }
  if (tid < 100) w2s[tid] = 2.f * fc2W[tid];
  __syncthreads();
  const int tx = tid & 31, ty = tid >> 5;
  float acc[4] = {0.f, 0.f, 0.f, 0.f};
#pragma unroll 4
  for (int k = 0; k < 100; ++k) {
    float b = Bs[tx][k];
    float wk2 = w2s[k];
    float bs = b * (2.f * LOG2E);
#pragma unroll
    for (int q = 0; q < 4; ++q) {
      float a = As[ty + 8 * q][k];
      float r = frcp(1.f + fexp2(__builtin_fmaf(a, 2.f * LOG2E, bs)));
      acc[q] = __builtin_fmaf(wk2, r, acc[q]);
    }
  }
  float base = sumw[0] + fc2b[0];
  const int j = j0 + tx;
#pragma unroll
  for (int q = 0; q < 4; ++q) {
    int i = i0 + ty + 8 * q;
    float val = (i != j && j != 0) ? (base - acc[q]) : 0.f;
    outS[(size_t)i * 1024 + j] = val;
    scoresT[(size_t)j * 1024 + i] = val;
  }
}

// ---------------- per-child log-softmax contribution -------------------------------
__global__ __launch_bounds__(256) void k_soft(const float* __restrict__ scoresT,
    const int* __restrict__ parents, float* __restrict__ contrib) {
  const int j = blockIdx.x, tid = threadIdx.x;
  __shared__ float red[256];
  const float* row = scoresT + (size_t)j * 1024;
  float v0 = row[tid], v1 = row[tid + 256], v2 = row[tid + 512], v3 = row[tid + 768];
  float m = fmaxf(fmaxf(v0, v1), fmaxf(v2, v3));
  red[tid] = m; __syncthreads();
  for (int off = 128; off; off >>= 1) {
    if (tid < off) red[tid] = fmaxf(red[tid], red[tid + off]);
    __syncthreads();
  }
  m = red[0]; __syncthreads();
  float s = fexp2((v0 - m) * LOG2E) + fexp2((v1 - m) * LOG2E) +
            fexp2((v2 - m) * LOG2E) + fexp2((v3 - m) * LOG2E);
  red[tid] = s; __syncthreads();
  for (int off = 128; off; off >>= 1) {
    if (tid < off) red[tid] += red[tid + off];
    __syncthreads();
  }
  if (tid == 0) {
    float S = red[0];
    int p = parents[j];
    contrib[j] = row[p] - m - flog2(S) * LN2;
  }
}

__global__ __launch_bounds__(256) void k_loss(const float* __restrict__ contrib,
                                              float* __restrict__ out) {
  __shared__ float red[256];
  int tid = threadIdx.x;
  float s = contrib[tid] + contrib[tid + 256] + contrib[tid + 512] + contrib[tid + 768];
  red[tid] = s; __syncthreads();
  for (int off = 128; off; off >>= 1) {
    if (tid < off) red[tid] += red[tid + off];
    __syncthreads();
  }
  if (tid == 0) out[0] = -red[0] * (1.f / 1024.f);
}

// ---------------- launcher ---------------------------------------------------------
extern "C" void kernel_launch(void* const* d_in, const int* in_sizes, int n_in,
                              void* d_out, int out_size, void* d_ws, size_t ws_size,
                              hipStream_t stream) {
  const float* wv   = (const float*)d_in[0];
  const int*   pidx = (const int*)d_in[1];
  const int*   par  = (const int*)d_in[2];
  const float* pemb = (const float*)d_in[3];
  const float* Wih0 = (const float*)d_in[4];
  const float* Whh0 = (const float*)d_in[5];
  const float* b0   = (const float*)d_in[6];
  const float* Wih1 = (const float*)d_in[7];
  const float* Whh1 = (const float*)d_in[8];
  const float* b1   = (const float*)d_in[9];
  const float* fc1W = (const float*)d_in[10];
  const float* fc1b = (const float*)d_in[11];
  const float* fc2W = (const float*)d_in[12];
  const float* fc2b = (const float*)d_in[13];
  float* ws = (float*)d_ws;
  // workspace layout (float offsets)
  float* X      = ws + 0;        // 1024*336
  float* Wih0p  = ws + 344064;   // 2*500*336
  float* Pq0    = ws + 680064;   // 2*125*1024*4 (gate-interleaved pre-gates L0)
  float* h0     = ws + 1704064;  // 1024*256
  float* Wih1p  = ws + 1966208;  // 2*500*256
  float* Pq1    = ws + 2222208;  // 2*125*1024*4 (gate-interleaved pre-gates L1)
  float* h1     = ws + 3246208;  // 1024*256
  float* Wab    = ws + 3508352;  // 200*256
  float* biasAB = ws + 3559552;  // 256
  float* AB     = ws + 3559808;  // 1024*200
  float* scT    = ws + 3764608;  // 1024*1024
  float* contrib= ws + 4813184;  // 1024
  float* sumw   = ws + 4814208;  // 1
  float* bs0    = ws + 4814212;  // 1000 (quarter-scaled biases L0)
  float* bs1    = ws + 4815212;  // 1000 (quarter-scaled biases L1)
  float* out = (float*)d_out;

  // zero padded h buffers (cols 250..255 must stay 0 for the K=256 GEMMs)
  hipMemsetAsync(h0, 0, 1024 * 256 * sizeof(float), stream);
  hipMemsetAsync(h1, 0, 1024 * 256 * sizeof(float), stream);

  k_prep<<<3241, 128, 0, stream>>>(wv, pidx, pemb, X, Wih0, Wih0p, Wih1, Wih1p,
                                   fc1W, Wab, fc1b, fc2W, biasAB, sumw,
                                   b0, bs0, b1, bs1);

  // layer 0 (pre-gates stored gate-interleaved: Pq[z][u][t][g])
  k_gemm<<<dim3(8, 16, 2), 256, 0, stream>>>(X, Wih0p, bs0, Pq0, 1024, 500, 336, 0,
                                             500L * 336, 500L * 1024, 500L, 2);
  k_rec <<<128, 512, 0, stream>>>(Pq0, Whh0, h0);
  // layer 1
  k_gemm<<<dim3(8, 16, 2), 256, 0, stream>>>(h0, Wih1p, bs1, Pq1, 1024, 500, 256, 0,
                                             500L * 256, 500L * 1024, 500L, 2);
  k_rec <<<128, 512, 0, stream>>>(Pq1, Whh1, h1);
  // head/child projections (fc1_b folded into head half via biasAB)
  k_gemm<<<dim3(4, 16, 1), 256, 0, stream>>>(h1, Wab, biasAB, AB, 1024, 200, 256, 200,
                                             0L, 0L, 0L, 0);
  // pairwise scores + transposed copy
  k_pair<<<dim3(32, 32), 256, 0, stream>>>(AB, fc2W, fc2b, sumw, out + 1, scT);
  // per-child log-softmax and loss
  k_soft<<<1024, 256, 0, stream>>>(scT, par, contrib);
  k_loss<<<1, 256, 0, stream>>>(contrib, out);
}

// Round 7
// 1372.381 us; speedup vs baseline: 1.0154x; 1.0154x over previous
//
#include <hip/hip_runtime.h>

typedef float v2f __attribute__((ext_vector_type(2)));
typedef float v4f __attribute__((ext_vector_type(4)));

#define LOG2E 1.4426950408889634f
#define LN2   0.6931471805599453f

__device__ __forceinline__ float fexp2(float x) {
  float r; asm("v_exp_f32 %0, %1" : "=v"(r) : "v"(x)); return r;
}
__device__ __forceinline__ float fexp2n(float x) {   // exp2(-x), modifier is free
  float r; asm("v_exp_f32 %0, -%1" : "=v"(r) : "v"(x)); return r;
}
__device__ __forceinline__ float frcp(float x) {
  float r; asm("v_rcp_f32 %0, %1" : "=v"(r) : "v"(x)); return r;
}
__device__ __forceinline__ float flog2(float x) {
  float r; asm("v_log_f32 %0, %1" : "=v"(r) : "v"(x)); return r;
}
// packed fp32 FMA, accumulate in place
__device__ __forceinline__ void pkfma(v2f& c, v2f a, v2f b) {
  asm("v_pk_fma_f32 %0, %1, %2, %0" : "+v"(c) : "v"(a), "v"(b));
}
// quad_perm lane swaps (VALU pipe)
__device__ __forceinline__ float dpp_xor1(float v) {
  return __builtin_bit_cast(float,
      __builtin_amdgcn_update_dpp(0, __builtin_bit_cast(int, v), 0xB1, 0xF, 0xF, true));
}
__device__ __forceinline__ float dpp_xor2(float v) {
  return __builtin_bit_cast(float,
      __builtin_amdgcn_update_dpp(0, __builtin_bit_cast(int, v), 0x4E, 0xF, 0xF, true));
}
// workgroup barrier WITHOUT vmcnt(0) drain: LDS ordering only
__device__ __forceinline__ void barrier_lgkm() {
  asm volatile("s_waitcnt lgkmcnt(0)\n\ts_barrier" ::: "memory");
}

// ---------------- fused prep: embed | repack0 | repack1 | wab | misc | bscale ------
__global__ __launch_bounds__(128) void k_prep(
    const float* __restrict__ wv, const int* __restrict__ pidx,
    const float* __restrict__ pemb, float* __restrict__ X,
    const float* __restrict__ Wih0, float* __restrict__ Wih0p,
    const float* __restrict__ Wih1, float* __restrict__ Wih1p,
    const float* __restrict__ fc1W, float* __restrict__ Wab,
    const float* __restrict__ fc1b, const float* __restrict__ fc2W,
    float* __restrict__ biasAB, float* __restrict__ sumw,
    const float* __restrict__ b0, float* __restrict__ bs0,
    const float* __restrict__ b1, float* __restrict__ bs1) {
  const int b = blockIdx.x, tid = threadIdx.x;
  if (b < 1024) {                       // embed
    int t = b, pi = pidx[t];
    for (int c = tid; c < 336; c += 128) {
      float v;
      if (c < 300)      v = wv[t * 300 + c];
      else if (c < 325) v = pemb[pi * 25 + (c - 300)];
      else              v = 0.f;
      X[t * 336 + c] = v;
    }
  } else if (b < 2024) {                // repack Wih0 (quarter-exp2 scale)
    int r = b - 1024;
    int gate = (r % 500) / 125;
    float sc = (gate == 2) ? 0.5f * LOG2E : 0.25f * LOG2E;
    for (int c = tid; c < 336; c += 128)
      Wih0p[r * 336 + c] = (c < 325) ? Wih0[r * 325 + c] * sc : 0.f;
  } else if (b < 3024) {                // repack Wih1
    int r = b - 2024;
    int gate = (r % 500) / 125;
    float sc = (gate == 2) ? 0.5f * LOG2E : 0.25f * LOG2E;
    for (int c = tid; c < 256; c += 128)
      Wih1p[r * 256 + c] = (c < 250) ? Wih1[r * 250 + c] * sc : 0.f;
  } else if (b < 3224) {                // wab split
    int r = b - 3024;
    int sr = (r < 100) ? r : r - 100;
    int so = (r < 100) ? 0 : 250;
    for (int c = tid; c < 256; c += 128)
      Wab[r * 256 + c] = (c < 250) ? fc1W[sr * 500 + so + c] : 0.f;
  } else if (b == 3224) {               // biasAB + sum(fc2W)
    __shared__ float red[128];
    for (int c = tid; c < 256; c += 128)
      biasAB[c] = (c < 100) ? fc1b[c] : 0.f;
    float s = (tid < 100) ? fc2W[tid] : 0.f;
    red[tid] = s; __syncthreads();
    for (int off = 64; off; off >>= 1) {
      if (tid < off) red[tid] += red[tid + off];
      __syncthreads();
    }
    if (tid == 0) sumw[0] = red[0];
  } else if (b < 3233) {                // bscale layer 0
    int i = (b - 3225) * 128 + tid;
    if (i < 1000) {
      int gate = (i % 500) / 125;
      bs0[i] = b0[i] * ((gate == 2) ? 0.5f * LOG2E : 0.25f * LOG2E);
    }
  } else {                              // bscale layer 1
    int i = (b - 3233) * 128 + tid;
    if (i < 1000) {
      int gate = (i % 500) / 125;
      bs1[i] = b1[i] * ((gate == 2) ? 0.5f * LOG2E : 0.25f * LOG2E);
    }
  }
}

// ---------------- tiled fp32 GEMM:  C = A @ B^T + bias -----------------------------
// transOut=0: C[m][n]. transOut=2: gate-interleaved scatter for k_rec:
//   C[(n%125)*4096 + m*4 + (n/125)]
#define BM 64
#define BN 64
#define BKK 16
__global__ __launch_bounds__(256) void k_gemm(
    const float* __restrict__ A, const float* __restrict__ Bw,
    const float* __restrict__ bias, float* __restrict__ C,
    int M, int N, int K, int ldC, long sBz, long sCz, long sbz, int transOut) {
  const int z = blockIdx.z;
  const float* Bp = Bw + (size_t)z * sBz;
  const float* bp = bias + (size_t)z * sbz;
  float* Cp = C + (size_t)z * sCz;
  const int bm = blockIdx.y * BM, bn = blockIdx.x * BN;
  __shared__ __align__(16) float As[BKK][BM + 4];
  __shared__ __align__(16) float Bs[BKK][BN + 4];
  const int tid = threadIdx.x;
  const int tx = tid & 15, ty = tid >> 4;
  const int lr = tid >> 2;            // 0..63
  const int lk = (tid & 3) * 4;       // 0,4,8,12
  float acc[4][4];
#pragma unroll
  for (int a = 0; a < 4; ++a)
#pragma unroll
    for (int b = 0; b < 4; ++b) acc[a][b] = 0.f;

  int brow = bn + lr; if (brow >= N) brow = N - 1;
  for (int k0 = 0; k0 < K; k0 += BKK) {
    float4 a4 = *(const float4*)(A + (size_t)(bm + lr) * K + k0 + lk);
    float4 b4 = *(const float4*)(Bp + (size_t)brow * K + k0 + lk);
    __syncthreads();
    As[lk + 0][lr] = a4.x; As[lk + 1][lr] = a4.y; As[lk + 2][lr] = a4.z; As[lk + 3][lr] = a4.w;
    Bs[lk + 0][lr] = b4.x; Bs[lk + 1][lr] = b4.y; Bs[lk + 2][lr] = b4.z; Bs[lk + 3][lr] = b4.w;
    __syncthreads();
#pragma unroll
    for (int kk = 0; kk < BKK; ++kk) {
      float4 av = *(const float4*)&As[kk][ty * 4];
      float4 bv = *(const float4*)&Bs[kk][tx * 4];
      float aa[4] = {av.x, av.y, av.z, av.w};
      float bb[4] = {bv.x, bv.y, bv.z, bv.w};
#pragma unroll
      for (int a = 0; a < 4; ++a)
#pragma unroll
        for (int b = 0; b < 4; ++b)
          acc[a][b] = __builtin_fmaf(aa[a], bb[b], acc[a][b]);
    }
  }
  if (transOut == 0) {
#pragma unroll
    for (int a = 0; a < 4; ++a) {
      int i = bm + ty * 4 + a;
#pragma unroll
      for (int b = 0; b < 4; ++b) {
        int j = bn + tx * 4 + b;
        if (j < N) Cp[(size_t)i * ldC + j] = acc[a][b] + bp[j];
      }
    }
  } else {
#pragma unroll
    for (int a = 0; a < 4; ++a) {
      int i = bm + ty * 4 + a;      // time
#pragma unroll
      for (int b = 0; b < 4; ++b) {
        int j = bn + tx * 4 + b;    // gate-row
        if (j < N) {
          int g = j / 125, u2 = j - g * 125;
          Cp[(size_t)u2 * 4096 + i * 4 + g] = acc[a][b] + bp[j];
        }
      }
    }
  }
}

// ---------------- LSTM recurrence v7 ----------------------------------------------
// v5 structure exactly (zero-conflict LDS, quad reduce-all, 1 lgkm barrier/step),
// 2 blocks, PLUS amdgpu_waves_per_eu(2,2): pins occupancy so the register
// allocator gets the full 256-VGPR/wave budget and keeps the 128-float weight
// array in ARCH VGPRs (round 2-6 showed VGPR_Count=100 + AGPR parking -> one
// v_accvgpr_read per pk_fma operand, ~2.4x VALU issue inflation).
#define REC_BODY(FWD)                                                              \
  {                                                                                \
    float cst = 0.f;                                                               \
    float4 cur[4], nxt[4];                                                         \
    _Pragma("unroll")                                                              \
    for (int e = 0; e < 4; ++e) cur[e] = Pr4[(FWD ? 0 : 1020) + e];                \
    __syncthreads();                                                               \
    for (int cb = 0; cb < 256; ++cb) {                                             \
      int nc = (cb + 1 < 256) ? cb + 1 : cb;                                       \
      int nb = FWD ? 4 * nc : 1020 - 4 * nc;                                       \
      _Pragma("unroll")                                                            \
      for (int e = 0; e < 4; ++e) nxt[e] = Pr4[nb + e];                            \
      _Pragma("unroll")                                                            \
      for (int e = 0; e < 4; ++e) {                                                \
        const int buf = e & 1;                                                     \
        float4 pre = cur[FWD ? e : 3 - e];                                         \
        const v4f* hp = (const v4f*)&hb[buf][36 * sub];                            \
        v2f a0 = {0.f, 0.f}, a1 = {0.f, 0.f}, a2 = {0.f, 0.f}, a3 = {0.f, 0.f};    \
        _Pragma("unroll")                                                          \
        for (int q = 0; q < 4; ++q) {                                              \
          v4f h1v = hp[2 * q], h2v = hp[2 * q + 1];                                \
          v2f ha = __builtin_shufflevector(h1v, h1v, 0, 1);                        \
          v2f hc = __builtin_shufflevector(h1v, h1v, 2, 3);                        \
          v2f he = __builtin_shufflevector(h2v, h2v, 0, 1);                        \
          v2f hg = __builtin_shufflevector(h2v, h2v, 2, 3);                        \
          pkfma(a0, w0[4 * q], ha); pkfma(a0, w0[4 * q + 1], hc);                  \
          pkfma(a0, w0[4 * q + 2], he); pkfma(a0, w0[4 * q + 3], hg);              \
          pkfma(a1, w1[4 * q], ha); pkfma(a1, w1[4 * q + 1], hc);                  \
          pkfma(a1, w1[4 * q + 2], he); pkfma(a1, w1[4 * q + 3], hg);              \
          pkfma(a2, w2[4 * q], ha); pkfma(a2, w2[4 * q + 1], hc);                  \
          pkfma(a2, w2[4 * q + 2], he); pkfma(a2, w2[4 * q + 3], hg);              \
          pkfma(a3, w3[4 * q], ha); pkfma(a3, w3[4 * q + 1], hc);                  \
          pkfma(a3, w3[4 * q + 2], he); pkfma(a3, w3[4 * q + 3], hg);              \
        }                                                                          \
        float p0 = a0.x + a0.y + pre.x;                                            \
        float p1 = a1.x + a1.y + pre.y;                                            \
        float p2 = a2.x + a2.y + pre.z;                                            \
        float p3 = a3.x + a3.y + pre.w;                                            \
        p0 += dpp_xor1(p0); p0 += dpp_xor2(p0);                                    \
        p1 += dpp_xor1(p1); p1 += dpp_xor2(p1);                                    \
        p2 += dpp_xor1(p2); p2 += dpp_xor2(p2);                                    \
        p3 += dpp_xor1(p3); p3 += dpp_xor2(p3);                                    \
        float gi = frcp(1.f + fexp2n(p0));                                         \
        float gf = frcp(1.f + fexp2n(p1));                                         \
        float gg2 = __builtin_fmaf(4.f * LOG2E, frcp(1.f + fexp2n(p2)),            \
                                   -2.f * LOG2E);                                  \
        float go = frcp(1.f + fexp2n(p3));                                         \
        cst = __builtin_fmaf(gf, cst, gi * gg2);   /* c scaled by 2*LOG2E */       \
        float th = __builtin_fmaf(2.f, frcp(1.f + fexp2n(cst)), -1.f);             \
        float h = go * th;                                                         \
        if (wr) {                                                                  \
          hb[buf ^ 1][u + 4 * (u >> 5)] = h;                                       \
          int step = 4 * cb + e;                                                   \
          int time = FWD ? step : 1023 - step;                                     \
          hout[(size_t)time * 256 + d * 125 + u] = h;                              \
        }                                                                          \
        barrier_lgkm();                                                            \
      }                                                                            \
      cur[0] = nxt[0]; cur[1] = nxt[1]; cur[2] = nxt[2]; cur[3] = nxt[3];          \
    }                                                                              \
  }

__global__ __launch_bounds__(512)
__attribute__((amdgpu_waves_per_eu(2, 2)))
void k_rec(const float* __restrict__ Pq,
           const float* __restrict__ Whh,
           float* __restrict__ hout) {
  const int d = blockIdx.x;
  const int t = threadIdx.x;
  int u = t >> 2; if (u > 124) u = 124;
  const int sub = t & 3;
  const bool wr = (sub == 0) && ((t >> 2) < 125);

  // weights: 4 gate rows x 32 cols (sub chunk) -> 128 VGPRs, exp2-domain scaled
  const float* Wd = Whh + (size_t)d * 500 * 125;
  v2f w0[16], w1[16], w2[16], w3[16];
#pragma unroll
  for (int j = 0; j < 16; ++j) {
    int col = sub * 32 + 2 * j;
    const float* r0 = Wd + (size_t)(0 * 125 + u) * 125;
    const float* r1 = Wd + (size_t)(1 * 125 + u) * 125;
    const float* r2 = Wd + (size_t)(2 * 125 + u) * 125;
    const float* r3 = Wd + (size_t)(3 * 125 + u) * 125;
    bool c0 = col < 125, c1 = col + 1 < 125;
    v2f a, b, c, dd;
    a.x  = c0 ? r0[col] * LOG2E : 0.f;          a.y  = c1 ? r0[col + 1] * LOG2E : 0.f;
    b.x  = c0 ? r1[col] * LOG2E : 0.f;          b.y  = c1 ? r1[col + 1] * LOG2E : 0.f;
    c.x  = c0 ? r2[col] * 2.f * LOG2E : 0.f;    c.y  = c1 ? r2[col + 1] * 2.f * LOG2E : 0.f;
    dd.x = c0 ? r3[col] * LOG2E : 0.f;          dd.y = c1 ? r3[col + 1] * LOG2E : 0.f;
    w0[j] = a; w1[j] = b; w2[j] = c; w3[j] = dd;
  }

  __shared__ __align__(16) float hb[2][160];   // padded: addr(c)=c+4*(c>>5)
  for (int i = t; i < 320; i += 512) ((float*)hb)[i] = 0.f;

  const float4* Pr4 = (const float4*)(Pq + (size_t)d * 500 * 1024) + (size_t)u * 1024;

  if (d == 0) REC_BODY(1)
  else        REC_BODY(0)
}

// ---------------- pairwise scorer ---------------------------------------------------
__global__ __launch_bounds__(256) void k_pair(const float* __restrict__ AB,
    const float* __restrict__ fc2W, const float* __restrict__ fc2b,
    const float* __restrict__ sumw, float* __restrict__ outS,
    float* __restrict__ scoresT) {
  __shared__ float As[32][100];
  __shared__ float Bs[32][101];
  __shared__ float w2s[100];
  const int tid = threadIdx.x;
  const int i0 = blockIdx.y * 32, j0 = blockIdx.x * 32;
  for (int idx = tid; idx < 3200; idx += 256) {
    int r = idx / 100, k = idx - r * 100;
    As[r][k] = AB[(size_t)(i0 + r) * 200 + k];
    Bs[r][k] = AB[(size_t)(j0 + r) * 200 + 100 + k];
  }
  if (tid < 100) w2s[tid] = 2.f * fc2W[tid];
  __syncthreads();
  const int tx = tid & 31, ty = tid >> 5;
  float acc[4] = {0.f, 0.f, 0.f, 0.f};
#pragma unroll 4
  for (int k = 0; k < 100; ++k) {
    float b = Bs[tx][k];
    float wk2 = w2s[k];
    float bs = b * (2.f * LOG2E);
#pragma unroll
    for (int q = 0; q < 4; ++q) {
      float a = As[ty + 8 * q][k];
      float r = frcp(1.f + fexp2(__builtin_fmaf(a, 2.f * LOG2E, bs)));
      acc[q] = __builtin_fmaf(wk2, r, acc[q]);
    }
  }
  float base = sumw[0] + fc2b[0];
  const int j = j0 + tx;
#pragma unroll
  for (int q = 0; q < 4; ++q) {
    int i = i0 + ty + 8 * q;
    float val = (i != j && j != 0) ? (base - acc[q]) : 0.f;
    outS[(size_t)i * 1024 + j] = val;
    scoresT[(size_t)j * 1024 + i] = val;
  }
}

// ---------------- per-child log-softmax contribution -------------------------------
__global__ __launch_bounds__(256) void k_soft(const float* __restrict__ scoresT,
    const int* __restrict__ parents, float* __restrict__ contrib) {
  const int j = blockIdx.x, tid = threadIdx.x;
  __shared__ float red[256];
  const float* row = scoresT + (size_t)j * 1024;
  float v0 = row[tid], v1 = row[tid + 256], v2 = row[tid + 512], v3 = row[tid + 768];
  float m = fmaxf(fmaxf(v0, v1), fmaxf(v2, v3));
  red[tid] = m; __syncthreads();
  for (int off = 128; off; off >>= 1) {
    if (tid < off) red[tid] = fmaxf(red[tid], red[tid + off]);
    __syncthreads();
  }
  m = red[0]; __syncthreads();
  float s = fexp2((v0 - m) * LOG2E) + fexp2((v1 - m) * LOG2E) +
            fexp2((v2 - m) * LOG2E) + fexp2((v3 - m) * LOG2E);
  red[tid] = s; __syncthreads();
  for (int off = 128; off; off >>= 1) {
    if (tid < off) red[tid] += red[tid + off];
    __syncthreads();
  }
  if (tid == 0) {
    float S = red[0];
    int p = parents[j];
    contrib[j] = row[p] - m - flog2(S) * LN2;
  }
}

__global__ __launch_bounds__(256) void k_loss(const float* __restrict__ contrib,
                                              float* __restrict__ out) {
  __shared__ float red[256];
  int tid = threadIdx.x;
  float s = contrib[tid] + contrib[tid + 256] + contrib[tid + 512] + contrib[tid + 768];
  red[tid] = s; __syncthreads();
  for (int off = 128; off; off >>= 1) {
    if (tid < off) red[tid] += red[tid + off];
    __syncthreads();
  }
  if (tid == 0) out[0] = -red[0] * (1.f / 1024.f);
}

// ---------------- launcher ---------------------------------------------------------
extern "C" void kernel_launch(void* const* d_in, const int* in_sizes, int n_in,
                              void* d_out, int out_size, void* d_ws, size_t ws_size,
                              hipStream_t stream) {
  const float* wv   = (const float*)d_in[0];
  const int*   pidx = (const int*)d_in[1];
  const int*   par  = (const int*)d_in[2];
  const float* pemb = (const float*)d_in[3];
  const float* Wih0 = (const float*)d_in[4];
  const float* Whh0 = (const float*)d_in[5];
  const float* b0   = (const float*)d_in[6];
  const float* Wih1 = (const float*)d_in[7];
  const float* Whh1 = (const float*)d_in[8];
  const float* b1   = (const float*)d_in[9];
  const float* fc1W = (const float*)d_in[10];
  const float* fc1b = (const float*)d_in[11];
  const float* fc2W = (const float*)d_in[12];
  const float* fc2b = (const float*)d_in[13];
  float* ws = (float*)d_ws;
  // workspace layout (float offsets)
  float* X      = ws + 0;        // 1024*336
  float* Wih0p  = ws + 344064;   // 2*500*336
  float* Pq0    = ws + 680064;   // 2*125*1024*4 (gate-interleaved pre-gates L0)
  float* h0     = ws + 1704064;  // 1024*256
  float* Wih1p  = ws + 1966208;  // 2*500*256
  float* Pq1    = ws + 2222208;  // 2*125*1024*4 (gate-interleaved pre-gates L1)
  float* h1     = ws + 3246208;  // 1024*256
  float* Wab    = ws + 3508352;  // 200*256
  float* biasAB = ws + 3559552;  // 256
  float* AB     = ws + 3559808;  // 1024*200
  float* scT    = ws + 3764608;  // 1024*1024
  float* contrib= ws + 4813184;  // 1024
  float* sumw   = ws + 4814208;  // 1
  float* bs0    = ws + 4814212;  // 1000 (quarter-scaled biases L0)
  float* bs1    = ws + 4815212;  // 1000 (quarter-scaled biases L1)
  float* out = (float*)d_out;

  // zero padded h buffers (cols 250..255 must stay 0 for the K=256 GEMMs)
  hipMemsetAsync(h0, 0, 1024 * 256 * sizeof(float), stream);
  hipMemsetAsync(h1, 0, 1024 * 256 * sizeof(float), stream);

  k_prep<<<3241, 128, 0, stream>>>(wv, pidx, pemb, X, Wih0, Wih0p, Wih1, Wih1p,
                                   fc1W, Wab, fc1b, fc2W, biasAB, sumw,
                                   b0, bs0, b1, bs1);

  // layer 0 (pre-gates stored gate-interleaved: Pq[z][u][t][g])
  k_gemm<<<dim3(8, 16, 2), 256, 0, stream>>>(X, Wih0p, bs0, Pq0, 1024, 500, 336, 0,
                                             500L * 336, 500L * 1024, 500L, 2);
  k_rec <<<2, 512, 0, stream>>>(Pq0, Whh0, h0);
  // layer 1
  k_gemm<<<dim3(8, 16, 2), 256, 0, stream>>>(h0, Wih1p, bs1, Pq1, 1024, 500, 256, 0,
                                             500L * 256, 500L * 1024, 500L, 2);
  k_rec <<<2, 512, 0, stream>>>(Pq1, Whh1, h1);
  // head/child projections (fc1_b folded into head half via biasAB)
  k_gemm<<<dim3(4, 16, 1), 256, 0, stream>>>(h1, Wab, biasAB, AB, 1024, 200, 256, 200,
                                             0L, 0L, 0L, 0);
  // pairwise scores + transposed copy
  k_pair<<<dim3(32, 32), 256, 0, stream>>>(AB, fc2W, fc2b, sumw, out + 1, scT);
  // per-child log-softmax and loss
  k_soft<<<1024, 256, 0, stream>>>(scT, par, contrib);
  k_loss<<<1, 256, 0, stream>>>(contrib, out);
}